// Round 1
// baseline (960.406 us; speedup 1.0000x reference)
//
#include <hip/hip_runtime.h>

#define TT    2048
#define DMOD  256
#define DK    64
#define NB    8
#define NH    4
#define MTOT  (NB * TT)          /* 16384 */
#define SCALE 0.125f             /* 1/sqrt(64) */

/* ws layout (float offsets) */
#define WS_QST 0u                /* qs transposed [64][16384] */
#define WS_KST 1048576u          /* ks transposed [64][16384] */
#define WS_VS  2097152u          /* vs row-major [16384][64]  */
#define WS_HT  3145728u          /* head transposed [64][16384] (normalized) */
#define WS_RL  4194304u          /* rcp row-sum [16384] */

#define ATTN_OFF ((size_t)MTOT * DMOD)     /* 4194304 */
#define HSTRIDE  ((size_t)NB * TT * TT)    /* 33554432 */
#define BSTRIDE  ((size_t)TT * TT)         /* 4194304 */

#define FMA16(ACC, Av, Bv)                                              \
  do {                                                                  \
    ACC[0][0] += (Av).x * (Bv).x; ACC[0][1] += (Av).x * (Bv).y;         \
    ACC[0][2] += (Av).x * (Bv).z; ACC[0][3] += (Av).x * (Bv).w;         \
    ACC[1][0] += (Av).y * (Bv).x; ACC[1][1] += (Av).y * (Bv).y;         \
    ACC[1][2] += (Av).y * (Bv).z; ACC[1][3] += (Av).y * (Bv).w;         \
    ACC[2][0] += (Av).z * (Bv).x; ACC[2][1] += (Av).z * (Bv).y;         \
    ACC[2][2] += (Av).z * (Bv).z; ACC[2][3] += (Av).z * (Bv).w;         \
    ACC[3][0] += (Av).w * (Bv).x; ACC[3][1] += (Av).w * (Bv).y;         \
    ACC[3][2] += (Av).w * (Bv).z; ACC[3][3] += (Av).w * (Bv).w;         \
  } while (0)

/* K1: qs/ks/vs projections. qs,ks stored TRANSPOSED [d][row] so the attention
   kernels can stage tiles with coalesced loads + linear LDS writes. */
__global__ __launch_bounds__(256) void k_proj(
    const float* __restrict__ q, const float* __restrict__ k,
    const float* __restrict__ v, const float* __restrict__ Wq,
    const float* __restrict__ Wk, const float* __restrict__ Wv,
    float* __restrict__ ws)
{
    const int which = blockIdx.y;
    const float* x = (which == 0) ? q : (which == 1) ? k : v;
    const float* W = (which == 0) ? Wq : (which == 1) ? Wk : Wv;
    float* outp = ws + ((which == 0) ? WS_QST : (which == 1) ? WS_KST : WS_VS);

    const int m0 = blockIdx.x * 64;
    const int t  = threadIdx.x;
    const int tx = t & 15, ty = t >> 4;

    __shared__ float At[64][68];   /* x tile transposed: At[k][row], pad 68 keeps 16B align */
    __shared__ float Wt[64][64];   /* W tile row-major [k][col] */

    float acc[4][4] = {};

    for (int kc = 0; kc < DMOD; kc += 64) {
        __syncthreads();
        #pragma unroll
        for (int j = 0; j < 4; ++j) {
            const int i  = t + 256 * j;
            const int r  = i >> 4;            /* 0..63 row */
            const int c4 = (i & 15) << 2;     /* 0..60 k */
            const float4 xv = *reinterpret_cast<const float4*>(
                &x[(size_t)(m0 + r) * DMOD + kc + c4]);
            At[c4 + 0][r] = xv.x; At[c4 + 1][r] = xv.y;
            At[c4 + 2][r] = xv.z; At[c4 + 3][r] = xv.w;
            *reinterpret_cast<float4*>(&Wt[r][c4]) =
                *reinterpret_cast<const float4*>(&W[(size_t)(kc + r) * DK + c4]);
        }
        __syncthreads();
        #pragma unroll
        for (int kk = 0; kk < 64; ++kk) {
            const float4 a = *reinterpret_cast<const float4*>(&At[kk][ty * 4]);
            const float4 b = *reinterpret_cast<const float4*>(&Wt[kk][tx * 4]);
            FMA16(acc, a, b);
        }
    }

    if (which < 2) {
        /* transposed store: outp[d][m0+row] */
        #pragma unroll
        for (int ci = 0; ci < 4; ++ci) {
            const float4 o = make_float4(acc[0][ci], acc[1][ci], acc[2][ci], acc[3][ci]);
            *reinterpret_cast<float4*>(&outp[(size_t)(tx * 4 + ci) * MTOT + m0 + ty * 4]) = o;
        }
    } else {
        /* vs row-major [row][d] */
        #pragma unroll
        for (int ri = 0; ri < 4; ++ri) {
            const float4 o = make_float4(acc[ri][0], acc[ri][1], acc[ri][2], acc[ri][3]);
            *reinterpret_cast<float4*>(&outp[(size_t)(m0 + ty * 4 + ri) * DK + tx * 4]) = o;
        }
    }
}

/* K2: flash-style pass (no max needed: |scores| <~ 6). Produces rcp row-sum
   and NORMALIZED head (transposed [d][row]) in ws. 64 query rows per WG. */
__global__ __launch_bounds__(256) void k_flash(float* __restrict__ ws)
{
    const float* qsT = ws + WS_QST;
    const float* ksT = ws + WS_KST;
    const float* vsp = ws + WS_VS;
    float* headT = ws + WS_HT;
    float* rl    = ws + WS_RL;

    const int m0 = blockIdx.x * 64;     /* global query row */
    const int b  = m0 >> 11;            /* batch (64 | 2048 so no straddle) */
    const int s_base = b * TT;
    const int t  = threadIdx.x;
    const int tx = t & 15, ty = t >> 4;

    __shared__ float qst[64][64];       /* [k][row] */
    __shared__ float kst[64][64];       /* [k][col] */
    __shared__ float vst[64][64];       /* [s][d]   */
    __shared__ float pt [64][68];       /* p transposed [col][row] */

    #pragma unroll
    for (int j = 0; j < 4; ++j) {
        const int i  = t + 256 * j;
        const int kk = i >> 4;
        const int r4 = (i & 15) << 2;
        *reinterpret_cast<float4*>(&qst[kk][r4]) =
            *reinterpret_cast<const float4*>(&qsT[(size_t)kk * MTOT + m0 + r4]);
    }

    float hacc[4][4] = {};
    float lacc[4] = {};

    for (int sc = 0; sc < TT; sc += 64) {
        __syncthreads();
        #pragma unroll
        for (int j = 0; j < 4; ++j) {
            const int i  = t + 256 * j;
            const int kk = i >> 4;
            const int c4 = (i & 15) << 2;
            *reinterpret_cast<float4*>(&kst[kk][c4]) =
                *reinterpret_cast<const float4*>(&ksT[(size_t)kk * MTOT + s_base + sc + c4]);
            *reinterpret_cast<float4*>(&vst[kk][c4]) =
                *reinterpret_cast<const float4*>(&vsp[(size_t)(s_base + sc + kk) * DK + c4]);
        }
        __syncthreads();

        float acc[4][4] = {};
        #pragma unroll
        for (int kk = 0; kk < 64; ++kk) {
            const float4 a  = *reinterpret_cast<const float4*>(&qst[kk][ty * 4]);
            const float4 bb = *reinterpret_cast<const float4*>(&kst[kk][tx * 4]);
            FMA16(acc, a, bb);
        }

        float p[4][4];
        #pragma unroll
        for (int ri = 0; ri < 4; ++ri) {
            #pragma unroll
            for (int ci = 0; ci < 4; ++ci) {
                const float e = __expf(acc[ri][ci] * SCALE);
                p[ri][ci] = e;
                lacc[ri] += e;
            }
        }
        /* write p transposed for the PV GEMM */
        #pragma unroll
        for (int ci = 0; ci < 4; ++ci) {
            const float4 o = make_float4(p[0][ci], p[1][ci], p[2][ci], p[3][ci]);
            *reinterpret_cast<float4*>(&pt[tx * 4 + ci][ty * 4]) = o;
        }
        __syncthreads();

        #pragma unroll
        for (int ss = 0; ss < 64; ++ss) {
            const float4 pp = *reinterpret_cast<const float4*>(&pt[ss][ty * 4]);
            const float4 vv = *reinterpret_cast<const float4*>(&vst[ss][tx * 4]);
            FMA16(hacc, pp, vv);
        }
    }

    /* reduce row sums across the 16 tx lanes (contiguous in-wave group) */
    #pragma unroll
    for (int ri = 0; ri < 4; ++ri) {
        float s = lacc[ri];
        s += __shfl_xor(s, 1);
        s += __shfl_xor(s, 2);
        s += __shfl_xor(s, 4);
        s += __shfl_xor(s, 8);
        lacc[ri] = 1.0f / s;
    }
    if (tx == 0) {
        #pragma unroll
        for (int ri = 0; ri < 4; ++ri)
            rl[m0 + ty * 4 + ri] = lacc[ri];
    }
    /* normalized head, transposed store headT[d][m0+row] */
    #pragma unroll
    for (int ci = 0; ci < 4; ++ci) {
        const float4 o = make_float4(hacc[0][ci] * lacc[0], hacc[1][ci] * lacc[1],
                                     hacc[2][ci] * lacc[2], hacc[3][ci] * lacc[3]);
        *reinterpret_cast<float4*>(&headT[(size_t)(tx * 4 + ci) * MTOT + m0 + ty * 4]) = o;
    }
}

/* K3: outputs = head @ Wo.  M=16384, K=64, N=256. */
__global__ __launch_bounds__(256) void k_out(const float* __restrict__ ws,
                                             const float* __restrict__ Wo,
                                             float* __restrict__ out)
{
    const float* headT = ws + WS_HT;
    const int m0 = blockIdx.x * 64;
    const int t  = threadIdx.x;
    const int tx = t & 15, ty = t >> 4;

    __shared__ float ht[64][64];     /* [k][row] */
    __shared__ float wo[64][256];    /* [k][col] */

    #pragma unroll
    for (int j = 0; j < 16; ++j) {
        const int i  = t + 256 * j;        /* float4 index 0..4095 */
        const int kk = i >> 6;
        const int c4 = (i & 63) << 2;
        *reinterpret_cast<float4*>(&wo[kk][c4]) =
            *reinterpret_cast<const float4*>(&Wo[(size_t)kk * DMOD + c4]);
    }
    #pragma unroll
    for (int j = 0; j < 4; ++j) {
        const int i  = t + 256 * j;
        const int kk = i >> 4;
        const int r4 = (i & 15) << 2;
        *reinterpret_cast<float4*>(&ht[kk][r4]) =
            *reinterpret_cast<const float4*>(&headT[(size_t)kk * MTOT + m0 + r4]);
    }
    __syncthreads();

    float4 acc[4][4] = {};   /* [row][col-group], col = j*64 + tx*4 */
    #pragma unroll
    for (int kk = 0; kk < 64; ++kk) {
        const float4 h = *reinterpret_cast<const float4*>(&ht[kk][ty * 4]);
        const float hr[4] = {h.x, h.y, h.z, h.w};
        #pragma unroll
        for (int j = 0; j < 4; ++j) {
            const float4 w = *reinterpret_cast<const float4*>(&wo[kk][j * 64 + tx * 4]);
            #pragma unroll
            for (int ri = 0; ri < 4; ++ri) {
                acc[ri][j].x += hr[ri] * w.x;
                acc[ri][j].y += hr[ri] * w.y;
                acc[ri][j].z += hr[ri] * w.z;
                acc[ri][j].w += hr[ri] * w.w;
            }
        }
    }
    #pragma unroll
    for (int ri = 0; ri < 4; ++ri) {
        #pragma unroll
        for (int j = 0; j < 4; ++j) {
            *reinterpret_cast<float4*>(
                &out[(size_t)(m0 + ty * 4 + ri) * DMOD + j * 64 + tx * 4]) = acc[ri][j];
        }
    }
}

/* K4: attn writer. Recomputes scores for a 64x64 (t,s) tile, p = exp(s)*rcp_l,
   streams the normalized probabilities to all 4 identical head slots. */
__global__ __launch_bounds__(256) void k_attn(const float* __restrict__ ws,
                                              float* __restrict__ out)
{
    const float* qsT = ws + WS_QST;
    const float* ksT = ws + WS_KST;
    const float* rl  = ws + WS_RL;
    float* attn = out + ATTN_OFF;

    const int tt0 = blockIdx.x * 64;
    const int ss0 = blockIdx.y * 64;
    const int b   = blockIdx.z;
    const int gq  = b * TT + tt0;
    const int gs  = b * TT + ss0;
    const int t   = threadIdx.x;
    const int tx  = t & 15, ty = t >> 4;

    __shared__ float qst[64][64];
    __shared__ float kst[64][64];

    #pragma unroll
    for (int j = 0; j < 4; ++j) {
        const int i  = t + 256 * j;
        const int kk = i >> 4;
        const int c4 = (i & 15) << 2;
        *reinterpret_cast<float4*>(&qst[kk][c4]) =
            *reinterpret_cast<const float4*>(&qsT[(size_t)kk * MTOT + gq + c4]);
        *reinterpret_cast<float4*>(&kst[kk][c4]) =
            *reinterpret_cast<const float4*>(&ksT[(size_t)kk * MTOT + gs + c4]);
    }
    __syncthreads();

    float acc[4][4] = {};
    #pragma unroll
    for (int kk = 0; kk < 64; ++kk) {
        const float4 a  = *reinterpret_cast<const float4*>(&qst[kk][ty * 4]);
        const float4 bb = *reinterpret_cast<const float4*>(&kst[kk][tx * 4]);
        FMA16(acc, a, bb);
    }

    float rlv[4];
    #pragma unroll
    for (int ri = 0; ri < 4; ++ri)
        rlv[ri] = rl[gq + ty * 4 + ri];

    #pragma unroll
    for (int ri = 0; ri < 4; ++ri) {
        const float4 o = make_float4(__expf(acc[ri][0] * SCALE) * rlv[ri],
                                     __expf(acc[ri][1] * SCALE) * rlv[ri],
                                     __expf(acc[ri][2] * SCALE) * rlv[ri],
                                     __expf(acc[ri][3] * SCALE) * rlv[ri]);
        const size_t rowoff = (size_t)b * BSTRIDE + (size_t)(tt0 + ty * 4 + ri) * TT
                            + ss0 + tx * 4;
        #pragma unroll
        for (int h = 0; h < NH; ++h)
            *reinterpret_cast<float4*>(&attn[(size_t)h * HSTRIDE + rowoff]) = o;
    }
}

extern "C" void kernel_launch(void* const* d_in, const int* in_sizes, int n_in,
                              void* d_out, int out_size, void* d_ws, size_t ws_size,
                              hipStream_t stream)
{
    const float* q  = (const float*)d_in[0];
    const float* k  = (const float*)d_in[1];
    const float* v  = (const float*)d_in[2];
    const float* Wq = (const float*)d_in[3];
    const float* Wk = (const float*)d_in[4];
    const float* Wv = (const float*)d_in[5];
    const float* Wo = (const float*)d_in[6];
    float* out = (float*)d_out;
    float* ws  = (float*)d_ws;

    k_proj<<<dim3(MTOT / 64, 3), 256, 0, stream>>>(q, k, v, Wq, Wk, Wv, ws);
    k_flash<<<dim3(MTOT / 64), 256, 0, stream>>>(ws);
    k_out<<<dim3(MTOT / 64), 256, 0, stream>>>(ws, Wo, out);
    k_attn<<<dim3(TT / 64, TT / 64, NB), 256, 0, stream>>>(ws, out);
}